// Round 3
// baseline (102.861 us; speedup 1.0000x reference)
//
#include <hip/hip_runtime.h>
#include <math.h>

#define HW 16384
#define NC 64
#define NB 16
#define CH 128              // k-chunks per batch (grid = NB*CH = 2048 blocks)
#define KB (HW / CH)        // 128 k per block
#define KC 64               // k per LDS stage
#define NIT (KB / KC)       // 2 stages per block

// ws layout (floats):
//   [0,1024)           S_v   (sum exp(vis) per row)
//   [1024,2048)        S_t
//   [2048,3072)        U_t   (sum exp(text)*text per row)
//   [3072,4096)        gw
//   [4096, 4096+npart*65536)  J_raw partial copies (npart x B x 64 x 64)

typedef __attribute__((ext_vector_type(8))) short bf16x8;
typedef __attribute__((ext_vector_type(8))) unsigned short u16x8;
typedef __attribute__((ext_vector_type(4))) float f32x4;

__device__ inline unsigned short f2bf(float x) {
  union { float f; unsigned u; } v; v.f = x;
  unsigned r = v.u + 0x7FFFu + ((v.u >> 16) & 1u);   // RNE (no NaN here: exp>0)
  return (unsigned short)(r >> 16);
}

__device__ inline float wave_reduce_sum(float v) {
#pragma unroll
  for (int o = 32; o > 0; o >>= 1) v += __shfl_down(v, o, 64);
  return v;
}

// LDS tile: 64 rows x 64 bf16, row stride 128B. XOR-swizzle 16B slots:
// slot(r, ko16) = ko16 ^ (r & 7)  -> ds_read_b128 across 16 rows = 2-way max.
__device__ inline int lds_off(int r, int ko16) {
  return r * 64 + ((ko16 ^ (r & 7)) << 3);   // in ushort units
}

__global__ __launch_bounds__(256) void joint_fused(const float* __restrict__ vis,
                                                   const float* __restrict__ text,
                                                   float* __restrict__ ws,
                                                   int jmask) {
  const int b = blockIdx.x / CH;
  const int chunk = blockIdx.x % CH;
  const int k0 = chunk * KB;

  __shared__ __align__(16) unsigned short lv[64 * 64];
  __shared__ __align__(16) unsigned short lt[64 * 64];

  const int t = threadIdx.x;
  const int w = t >> 6;           // wave 0..3
  const int l = t & 63;
  const int r = w * 16 + (l >> 2);  // staging row 0..63
  const int kq = l & 3;             // 16-float quarter of the 64-k stage

  const float* vrow = vis  + ((size_t)b * NC + r) * HW + k0 + kq * 16;
  const float* trow = text + ((size_t)b * NC + r) * HW + k0 + kq * 16;

  float4 rv0, rv1, rv2, rv3, rt0, rt1, rt2, rt3;
  {
    const float4* pv = (const float4*)vrow;
    const float4* pt = (const float4*)trow;
    rv0 = pv[0]; rv1 = pv[1]; rv2 = pv[2]; rv3 = pv[3];
    rt0 = pt[0]; rt1 = pt[1]; rt2 = pt[2]; rt3 = pt[3];
  }

  float sv = 0.f, st = 0.f, ut = 0.f;
  f32x4 acc0 = {0.f,0.f,0.f,0.f}, acc1 = {0.f,0.f,0.f,0.f};
  f32x4 acc2 = {0.f,0.f,0.f,0.f}, acc3 = {0.f,0.f,0.f,0.f};

  const int mrow = w * 16 + (l & 15);  // A row this wave reads
  const int kol  = l >> 4;             // 0..3 (k 16B-slot within k-step)

#pragma unroll
  for (int it = 0; it < NIT; ++it) {
    // --- exp + cvt + stats (consumes prefetched regs) ---
    u16x8 ev0, ev1, et0, et1;
#define DOV(V, DST, J0) { \
    float e0=__expf(V.x), e1=__expf(V.y), e2=__expf(V.z), e3=__expf(V.w); \
    sv += (e0+e1)+(e2+e3); \
    DST[J0+0]=(short)f2bf(e0); DST[J0+1]=(short)f2bf(e1); \
    DST[J0+2]=(short)f2bf(e2); DST[J0+3]=(short)f2bf(e3); }
#define DOT(V, DST, J0) { \
    float e0=__expf(V.x), e1=__expf(V.y), e2=__expf(V.z), e3=__expf(V.w); \
    st += (e0+e1)+(e2+e3); \
    ut += (e0*V.x+e1*V.y)+(e2*V.z+e3*V.w); \
    DST[J0+0]=(short)f2bf(e0); DST[J0+1]=(short)f2bf(e1); \
    DST[J0+2]=(short)f2bf(e2); DST[J0+3]=(short)f2bf(e3); }
    DOV(rv0, ev0, 0) DOV(rv1, ev0, 4) DOV(rv2, ev1, 0) DOV(rv3, ev1, 4)
    DOT(rt0, et0, 0) DOT(rt1, et0, 4) DOT(rt2, et1, 0) DOT(rt3, et1, 4)
#undef DOV
#undef DOT

    __syncthreads();   // all waves finished reading LDS of previous stage

    // --- stage to LDS (swizzled) ---
    *reinterpret_cast<u16x8*>(&lv[lds_off(r, kq*2    )]) = ev0;
    *reinterpret_cast<u16x8*>(&lv[lds_off(r, kq*2 + 1)]) = ev1;
    *reinterpret_cast<u16x8*>(&lt[lds_off(r, kq*2    )]) = et0;
    *reinterpret_cast<u16x8*>(&lt[lds_off(r, kq*2 + 1)]) = et1;

    // --- prefetch next stage (stays in flight across the raw barrier) ---
    if (it + 1 < NIT) {
      const float4* pv = (const float4*)(vrow + (it + 1) * KC);
      const float4* pt = (const float4*)(trow + (it + 1) * KC);
      rv0 = pv[0]; rv1 = pv[1]; rv2 = pv[2]; rv3 = pv[3];
      rt0 = pt[0]; rt1 = pt[1]; rt2 = pt[2]; rt3 = pt[3];
    }

    asm volatile("s_waitcnt lgkmcnt(0)" ::: "memory");  // ds_writes visible
    __builtin_amdgcn_s_barrier();                        // no vmcnt drain
    asm volatile("" ::: "memory");

    // --- MFMA: wave w owns A-rows [16w,16w+16); 4 B tiles cover n=0..63 ---
#pragma unroll
    for (int s = 0; s < 2; ++s) {
      int ko = s * 4 + kol;
      bf16x8 a = *reinterpret_cast<const bf16x8*>(&lv[lds_off(mrow, ko)]);
      bf16x8 b0 = *reinterpret_cast<const bf16x8*>(&lt[lds_off( 0 + (l & 15), ko)]);
      bf16x8 b1 = *reinterpret_cast<const bf16x8*>(&lt[lds_off(16 + (l & 15), ko)]);
      bf16x8 b2 = *reinterpret_cast<const bf16x8*>(&lt[lds_off(32 + (l & 15), ko)]);
      bf16x8 b3 = *reinterpret_cast<const bf16x8*>(&lt[lds_off(48 + (l & 15), ko)]);
      acc0 = __builtin_amdgcn_mfma_f32_16x16x32_bf16(a, b0, acc0, 0, 0, 0);
      acc1 = __builtin_amdgcn_mfma_f32_16x16x32_bf16(a, b1, acc1, 0, 0, 0);
      acc2 = __builtin_amdgcn_mfma_f32_16x16x32_bf16(a, b2, acc2, 0, 0, 0);
      acc3 = __builtin_amdgcn_mfma_f32_16x16x32_bf16(a, b3, acc3, 0, 0, 0);
    }
  }

  // --- stats: quad lanes (same row) reduce, one atomic per row ---
  sv += __shfl_xor(sv, 1, 64); sv += __shfl_xor(sv, 2, 64);
  st += __shfl_xor(st, 1, 64); st += __shfl_xor(st, 2, 64);
  ut += __shfl_xor(ut, 1, 64); ut += __shfl_xor(ut, 2, 64);
  if ((l & 3) == 0) {
    atomicAdd(&ws[b * 64 + r], sv);
    atomicAdd(&ws[1024 + b * 64 + r], st);
    atomicAdd(&ws[2048 + b * 64 + r], ut);
  }

  // --- J_raw accumulate into partial copy (chunk & jmask) ---
  // C/D layout col=l&15, row=(l>>4)*4+reg (m89)
  float* J = ws + 4096 + ((size_t)((chunk & jmask) * NB + b)) * 4096;
  const int m0 = w * 16 + (l >> 4) * 4;
  const int n0 = l & 15;
#pragma unroll
  for (int reg = 0; reg < 4; ++reg) {
    atomicAdd(&J[(m0 + reg) * 64 +  0 + n0], acc0[reg]);
    atomicAdd(&J[(m0 + reg) * 64 + 16 + n0], acc1[reg]);
    atomicAdd(&J[(m0 + reg) * 64 + 32 + n0], acc2[reg]);
    atomicAdd(&J[(m0 + reg) * 64 + 48 + n0], acc3[reg]);
  }
}

__global__ __launch_bounds__(256) void mi_gw_kernel(const float* __restrict__ ws,
                                                    float* __restrict__ gw,
                                                    int npart) {
  const int b = blockIdx.x;
  const int t = threadIdx.x;
  __shared__ float sSv[64], sSt[64];
  if (t < 64) sSv[t] = ws[b * 64 + t];
  else if (t < 128) sSt[t - 64] = ws[1024 + b * 64 + (t - 64)];
  __syncthreads();

  const float HW2 = (float)HW * (float)HW;
  float part = 0.f;
  for (int i = t; i < 4096; i += 256) {
    float jr = 0.f;
    for (int p = 0; p < npart; ++p)
      jr += ws[4096 + ((size_t)(p * NB + b)) * 4096 + i];
    int c = i >> 6, d = i & 63;
    float q = jr * (HW2 / (sSv[c] * sSt[d]));   // Q = HW^2 * joint
    part += q * __logf(q + 1e-9f);
  }
  part = wave_reduce_sum(part);
  __shared__ float sh[4];
  __shared__ float mi_sh;
  int wid = t >> 6, lane = t & 63;
  if (lane == 0) sh[wid] = part;
  __syncthreads();
  if (t == 0) mi_sh = ((sh[0] + sh[1]) + (sh[2] + sh[3])) / HW2;
  __syncthreads();
  if (t < 64) {
    float S = sSt[t];
    float U = ws[2048 + b * 64 + t];
    float ent = __logf(S) - U / S;                // text spatial entropy
    float z = 1.0f - ent + 0.5f * mi_sh;
    gw[b * 64 + t] = 1.0f / (1.0f + __expf(-z));
  }
}

__global__ __launch_bounds__(256) void enhance_kernel(const float4* __restrict__ vis,
                                                      const float4* __restrict__ text,
                                                      const float* __restrict__ gw,
                                                      float4* __restrict__ out) {
  const size_t total4 = (size_t)NB * NC * HW / 4;   // 4194304
  for (size_t i = (size_t)blockIdx.x * 256 + threadIdx.x; i < total4;
       i += (size_t)gridDim.x * 256) {
    float4 v = vis[i];
    float4 t = text[i];
    float g = gw[i >> 12];              // 4096 float4 per (b,c) row
    out[i] = make_float4(v.x + g * t.x, v.y + g * t.y,
                         v.z + g * t.z, v.w + g * t.w);
  }
}

extern "C" void kernel_launch(void* const* d_in, const int* in_sizes, int n_in,
                              void* d_out, int out_size, void* d_ws, size_t ws_size,
                              hipStream_t stream) {
  const float* vis  = (const float*)d_in[0];
  const float* text = (const float*)d_in[1];
  float* out = (float*)d_out;
  float* ws  = (float*)d_ws;
  float* gw  = ws + 3072;

  // choose number of J partial copies from available scratch (deterministic)
  size_t ws_floats = ws_size / sizeof(float);
  int npart = 1;
  if (ws_floats >= 4096 + 4 * 65536) npart = 4;
  else if (ws_floats >= 4096 + 2 * 65536) npart = 2;

  // zero stats + gw + J partials
  hipMemsetAsync(ws, 0, (4096 + (size_t)npart * 65536) * sizeof(float), stream);

  joint_fused<<<NB * CH, 256, 0, stream>>>(vis, text, ws, npart - 1);
  mi_gw_kernel<<<NB, 256, 0, stream>>>(ws, gw, npart);
  enhance_kernel<<<2048, 256, 0, stream>>>((const float4*)vis, (const float4*)text,
                                           gw, (float4*)out);
}